// Round 1
// baseline (1949.307 us; speedup 1.0000x reference)
//
#include <hip/hip_runtime.h>
#include <cstdint>
#include <cstddef>

#define WAVE 64

// ---------------- CSR construction ----------------

__global__ __launch_bounds__(256) void k_count(const int* __restrict__ dst, int* __restrict__ cnt,
                                               const float* __restrict__ w, float* __restrict__ deg, int E) {
    int e = blockIdx.x * 256 + threadIdx.x;
    if (e < E) {
        int d = dst[e];
        atomicAdd(&cnt[d], 1);
        if (w) atomicAdd(&deg[d], w[e]);
    }
}

// inclusive scan within blocks of 256
__global__ __launch_bounds__(256) void k_scan1(const int* __restrict__ cnt, int* __restrict__ incl,
                                               int* __restrict__ bsums, int n) {
    __shared__ int sm[256];
    int i = blockIdx.x * 256 + threadIdx.x;
    int v = (i < n) ? cnt[i] : 0;
    sm[threadIdx.x] = v;
    __syncthreads();
    for (int off = 1; off < 256; off <<= 1) {
        int t = (threadIdx.x >= off) ? sm[threadIdx.x - off] : 0;
        __syncthreads();
        sm[threadIdx.x] += t;
        __syncthreads();
    }
    if (i < n) incl[i] = sm[threadIdx.x];
    if (threadIdx.x == 255) bsums[blockIdx.x] = sm[255];
}

// single-block exclusive scan of block sums (nb <= 512)
__global__ __launch_bounds__(512) void k_scan2(int* __restrict__ bsums, int nb) {
    __shared__ int sm[512];
    int v = (threadIdx.x < nb) ? bsums[threadIdx.x] : 0;
    sm[threadIdx.x] = v;
    __syncthreads();
    for (int off = 1; off < 512; off <<= 1) {
        int t = (threadIdx.x >= off) ? sm[threadIdx.x - off] : 0;
        __syncthreads();
        sm[threadIdx.x] += t;
        __syncthreads();
    }
    if (threadIdx.x < nb) bsums[threadIdx.x] = sm[threadIdx.x] - v;  // exclusive
}

__global__ __launch_bounds__(256) void k_scan3(const int* __restrict__ incl, const int* __restrict__ cnt,
                                               const int* __restrict__ boff, int* __restrict__ rowp,
                                               int* __restrict__ cur, int n, int Etot) {
    int i = blockIdx.x * 256 + threadIdx.x;
    if (i < n) {
        int ex = incl[i] - cnt[i] + boff[blockIdx.x];
        rowp[i] = ex;
        cur[i] = ex;
    }
    if (i == 0) rowp[n] = Etot;
}

__global__ __launch_bounds__(256) void k_scatter(const int* __restrict__ src, const int* __restrict__ dst,
                                                 const float* __restrict__ w, int* __restrict__ cur,
                                                 int* __restrict__ csrc, float* __restrict__ cw, int E) {
    int e = blockIdx.x * 256 + threadIdx.x;
    if (e < E) {
        int d = dst[e];
        int pos = atomicAdd(&cur[d], 1);
        csrc[pos] = src[e];
        if (w) cw[pos] = w[e];
    }
}

__global__ __launch_bounds__(256) void k_dinv(const float* __restrict__ deg, float* __restrict__ dinv, int N) {
    int i = blockIdx.x * 256 + threadIdx.x;
    if (i < N) dinv[i] = rsqrtf(deg[i] + 1.0f);  // +1 = self-loop weight; always > 0
}

// ---------------- SGEMM: C[N,M] = A[N,K] * B[K,M] ----------------
// 128x64 block tile, 16 k-tile, 256 threads, 8x4 microtile.

#define GM 128
#define GN 64
#define GK 16

__global__ __launch_bounds__(256) void k_sgemm(const float* __restrict__ A, const float* __restrict__ B,
                                               float* __restrict__ C, int N, int K, int M) {
    __shared__ float As[GK][GM + 1];
    __shared__ float Bs[GK][GN + 1];
    int tid = threadIdx.x;
    int ty = tid >> 4;        // 0..15
    int tx = tid & 15;        // 0..15
    int rowBase = blockIdx.y * GM;
    int colBase = blockIdx.x * GN;
    int row0 = rowBase + ty * 8;
    int col0 = colBase + tx * 4;

    float acc[8][4] = {};

    for (int k0 = 0; k0 < K; k0 += GK) {
        // load A tile: k = tid&15 (coalesced along K), rows = (tid>>4) + i*16
        {
            int ka = tid & 15;
            int rb = tid >> 4;
            int gk = k0 + ka;
            bool kok = (gk < K);
#pragma unroll
            for (int i = 0; i < 8; i++) {
                int r = rb + i * 16;
                int gr = rowBase + r;
                As[ka][r] = (kok && gr < N) ? A[(size_t)gr * K + gk] : 0.f;
            }
        }
        // load B tile: cols coalesced
        {
            int cb = tid & 63;
            int kb = tid >> 6;  // 0..3
            int gc = colBase + cb;
            bool cok = (gc < M);
#pragma unroll
            for (int i = 0; i < 4; i++) {
                int kk = kb * 4 + i;
                int gk = k0 + kk;
                Bs[kk][cb] = (cok && gk < K) ? B[(size_t)gk * M + gc] : 0.f;
            }
        }
        __syncthreads();
#pragma unroll
        for (int kk = 0; kk < GK; kk++) {
            float a[8], b[4];
#pragma unroll
            for (int i = 0; i < 8; i++) a[i] = As[kk][ty * 8 + i];
#pragma unroll
            for (int j = 0; j < 4; j++) b[j] = Bs[kk][tx * 4 + j];
#pragma unroll
            for (int i = 0; i < 8; i++)
#pragma unroll
                for (int j = 0; j < 4; j++) acc[i][j] += a[i] * b[j];
        }
        __syncthreads();
    }

#pragma unroll
    for (int i = 0; i < 8; i++) {
        int r = row0 + i;
        if (r < N) {
#pragma unroll
            for (int j = 0; j < 4; j++) {
                int c = col0 + j;
                if (c < M) C[(size_t)r * M + c] = acc[i][j];
            }
        }
    }
}

// ---------------- per-node attention dots ----------------
// one wave per node: alpha_s[n,h] = sum_c h[n,h,c]*a_src[h,c]; same for a_dst

template <int H>
__global__ __launch_bounds__(64) void k_node_alpha(const float* __restrict__ hfeat,
                                                   const float* __restrict__ a_src,
                                                   const float* __restrict__ a_dst,
                                                   float* __restrict__ as_out, float* __restrict__ ad_out,
                                                   int C) {
    int n = blockIdx.x;
    int lane = threadIdx.x;
    int HC = H * C;
    float ps[H], pd[H];
#pragma unroll
    for (int h = 0; h < H; h++) { ps[h] = 0.f; pd[h] = 0.f; }
    for (int c = lane; c < HC; c += 64) {
        float v = hfeat[(size_t)n * HC + c];
        int hd = c / C;
        ps[hd] += v * a_src[c];
        pd[hd] += v * a_dst[c];
    }
#pragma unroll
    for (int h = 0; h < H; h++) {
        float x = ps[h], y = pd[h];
        for (int off = 32; off > 0; off >>= 1) {
            x += __shfl_down(x, off);
            y += __shfl_down(y, off);
        }
        if (lane == 0) {
            as_out[(size_t)n * H + h] = x;
            ad_out[(size_t)n * H + h] = y;
        }
    }
}

// ---------------- GAT aggregation (one wave per dst node) ----------------

__device__ __forceinline__ float lrelu02(float e) { return (e > 0.f) ? e : 0.2f * e; }

template <int CPT, int H>
__global__ __launch_bounds__(64) void k_gat_agg(const float* __restrict__ hfeat,
                                                const float* __restrict__ as_, const float* __restrict__ ad_,
                                                const int* __restrict__ rowp, const int* __restrict__ cidx,
                                                const float* __restrict__ bias, float* __restrict__ out,
                                                int C, int relu) {
    int n = blockIdx.x;
    int lane = threadIdx.x;
    int HC = H * C;
    int beg = rowp[n], end = rowp[n + 1];

    int hd[CPT];
#pragma unroll
    for (int k = 0; k < CPT; k++) {
        int c = lane + k * WAVE;
        hd[k] = (c < HC) ? (c / C) : 0;
    }

    float adn[H], m[H];
#pragma unroll
    for (int h = 0; h < H; h++) {
        adn[h] = ad_[(size_t)n * H + h];
        m[h] = lrelu02(as_[(size_t)n * H + h] + adn[h]);  // self-loop logit
    }
    // pass 1: segment max
    for (int j = beg; j < end; j++) {
        int s = cidx[j];
#pragma unroll
        for (int h = 0; h < H; h++) {
            float e = lrelu02(as_[(size_t)s * H + h] + adn[h]);
            m[h] = fmaxf(m[h], e);
        }
    }
    // pass 2: exp-sum + weighted feature accumulate (self-loop first)
    float acc[CPT];
#pragma unroll
    for (int k = 0; k < CPT; k++) acc[k] = 0.f;
    float ssum[H];
#pragma unroll
    for (int h = 0; h < H; h++) ssum[h] = 0.f;
    {
        float w[H];
#pragma unroll
        for (int h = 0; h < H; h++) {
            float e = lrelu02(as_[(size_t)n * H + h] + adn[h]);
            w[h] = expf(e - m[h]);
            ssum[h] += w[h];
        }
#pragma unroll
        for (int k = 0; k < CPT; k++) {
            int c = lane + k * WAVE;
            if (c < HC) acc[k] += w[hd[k]] * hfeat[(size_t)n * HC + c];
        }
    }
    for (int j = beg; j < end; j++) {
        int s = cidx[j];
        float w[H];
#pragma unroll
        for (int h = 0; h < H; h++) {
            float e = lrelu02(as_[(size_t)s * H + h] + adn[h]);
            w[h] = expf(e - m[h]);
            ssum[h] += w[h];
        }
#pragma unroll
        for (int k = 0; k < CPT; k++) {
            int c = lane + k * WAVE;
            if (c < HC) acc[k] += w[hd[k]] * hfeat[(size_t)s * HC + c];
        }
    }
#pragma unroll
    for (int k = 0; k < CPT; k++) {
        int c = lane + k * WAVE;
        if (c < HC) {
            float o = acc[k] / (ssum[hd[k]] + 1e-16f) + bias[c];
            if (relu) o = fmaxf(o, 0.f);
            out[(size_t)n * HC + c] = o;
        }
    }
}

// ---------------- GCN aggregation (one wave per dst node, C<=64) ----------------

__global__ __launch_bounds__(64) void k_gcn_agg(const float* __restrict__ hfeat, const float* __restrict__ dinv,
                                                const int* __restrict__ rowp, const int* __restrict__ cidx,
                                                const float* __restrict__ cw, const float* __restrict__ bias,
                                                float* __restrict__ out, int C) {
    int n = blockIdx.x;
    int lane = threadIdx.x;
    float di = dinv[n];
    int beg = rowp[n], end = rowp[n + 1];
    float acc = 0.f;
    bool act = (lane < C);
    if (act) acc = di * di * hfeat[(size_t)n * C + lane];  // self loop, w=1
    for (int j = beg; j < end; j++) {
        int s = cidx[j];
        float nm = dinv[s] * cw[j] * di;
        if (act) acc += nm * hfeat[(size_t)s * C + lane];
    }
    if (act) out[(size_t)n * C + lane] = fmaxf(acc + bias[lane], 0.f);  // relu after GCN
}

// ---------------- launch ----------------

extern "C" void kernel_launch(void* const* d_in, const int* in_sizes, int n_in,
                              void* d_out, int out_size, void* d_ws, size_t ws_size,
                              hipStream_t stream) {
    const int N_MOL = in_sizes[0] / 78;
    const int E_MOL = in_sizes[1] / 2;
    const int N_PRO = in_sizes[2] / 33;
    const int E_PRO = in_sizes[3] / 2;

    const float* mol_x = (const float*)d_in[0];
    const int* mol_ei = (const int*)d_in[1];
    const float* pro_x = (const float*)d_in[2];
    const int* pro_ei = (const int*)d_in[3];
    const float* pro_ew = (const float*)d_in[4];
    const float *W1 = (const float*)d_in[5], *as1 = (const float*)d_in[6], *ad1 = (const float*)d_in[7],
                *b1 = (const float*)d_in[8];
    const float *W2 = (const float*)d_in[9], *as2 = (const float*)d_in[10], *ad2 = (const float*)d_in[11],
                *b2 = (const float*)d_in[12];
    const float *W3 = (const float*)d_in[13], *as3 = (const float*)d_in[14], *ad3 = (const float*)d_in[15],
                *b3 = (const float*)d_in[16];
    const float *Wp1 = (const float*)d_in[17], *bp1 = (const float*)d_in[18];
    const float *Wp2 = (const float*)d_in[19], *aps2 = (const float*)d_in[20], *apd2 = (const float*)d_in[21],
                *bp2 = (const float*)d_in[22];
    const float *Wp3 = (const float*)d_in[23], *aps3 = (const float*)d_in[24], *apd3 = (const float*)d_in[25],
                *bp3 = (const float*)d_in[26];

    float* out_mol = (float*)d_out;
    float* out_pro = (float*)d_out + (size_t)N_MOL * 312;

    // workspace bump allocator (256B aligned)
    char* p = (char*)d_ws;
    auto alloc = [&](size_t bytes) -> void* {
        void* r = (void*)p;
        p += (bytes + 255) & ~(size_t)255;
        return r;
    };
    int* mol_rowp = (int*)alloc((size_t)(N_MOL + 1) * 4);
    int* mol_cur  = (int*)alloc((size_t)N_MOL * 4);
    int* mol_cnt  = (int*)alloc((size_t)N_MOL * 4);
    int* mol_csrc = (int*)alloc((size_t)E_MOL * 4);
    int* pro_rowp = (int*)alloc((size_t)(N_PRO + 1) * 4);
    int* pro_cur  = (int*)alloc((size_t)N_PRO * 4);
    int* pro_cnt  = (int*)alloc((size_t)N_PRO * 4);
    int* pro_csrc = (int*)alloc((size_t)E_PRO * 4);
    float* pro_csrw = (float*)alloc((size_t)E_PRO * 4);
    float* deg  = (float*)alloc((size_t)N_PRO * 4);
    float* dinv = (float*)alloc((size_t)N_PRO * 4);
    int* incl  = (int*)alloc((size_t)N_PRO * 4);
    int* bsums = (int*)alloc(512 * 4);
    float* asb = (float*)alloc((size_t)N_PRO * 2 * 4);
    float* adb = (float*)alloc((size_t)N_PRO * 2 * 4);
    float* bufA = (float*)alloc((size_t)N_MOL * 312 * 4);  // 15.6M floats
    float* bufB = (float*)alloc((size_t)N_MOL * 156 * 4);  // 7.8M floats
    float* bufC = (float*)alloc((size_t)N_MOL * 312 * 4);  // 15.6M floats
    (void)ws_size;

    const int* mol_src = mol_ei;
    const int* mol_dst = mol_ei + E_MOL;
    const int* pro_src = pro_ei;
    const int* pro_dst = pro_ei + E_PRO;

    // ---- build CSR (by dst) for both graphs ----
    hipMemsetAsync(mol_cnt, 0, (size_t)N_MOL * 4, stream);
    hipMemsetAsync(pro_cnt, 0, (size_t)N_PRO * 4, stream);
    hipMemsetAsync(deg, 0, (size_t)N_PRO * 4, stream);

    k_count<<<(E_MOL + 255) / 256, 256, 0, stream>>>(mol_dst, mol_cnt, nullptr, nullptr, E_MOL);
    k_count<<<(E_PRO + 255) / 256, 256, 0, stream>>>(pro_dst, pro_cnt, pro_ew, deg, E_PRO);

    int nbM = (N_MOL + 255) / 256;
    k_scan1<<<nbM, 256, 0, stream>>>(mol_cnt, incl, bsums, N_MOL);
    k_scan2<<<1, 512, 0, stream>>>(bsums, nbM);
    k_scan3<<<nbM, 256, 0, stream>>>(incl, mol_cnt, bsums, mol_rowp, mol_cur, N_MOL, E_MOL);
    k_scatter<<<(E_MOL + 255) / 256, 256, 0, stream>>>(mol_src, mol_dst, nullptr, mol_cur, mol_csrc, nullptr, E_MOL);

    int nbP = (N_PRO + 255) / 256;
    k_scan1<<<nbP, 256, 0, stream>>>(pro_cnt, incl, bsums, N_PRO);
    k_scan2<<<1, 512, 0, stream>>>(bsums, nbP);
    k_scan3<<<nbP, 256, 0, stream>>>(incl, pro_cnt, bsums, pro_rowp, pro_cur, N_PRO, E_PRO);
    k_scatter<<<(E_PRO + 255) / 256, 256, 0, stream>>>(pro_src, pro_dst, pro_ew, pro_cur, pro_csrc, pro_csrw, E_PRO);

    k_dinv<<<(N_PRO + 255) / 256, 256, 0, stream>>>(deg, dinv, N_PRO);

    auto gemm = [&](const float* A, const float* B, float* C, int N, int K, int M) {
        dim3 grid((M + GN - 1) / GN, (N + GM - 1) / GM);
        k_sgemm<<<grid, 256, 0, stream>>>(A, B, C, N, K, M);
    };

    // ---- mol branch ----
    // conv1: GAT 78 -> 78, H=2 (HC=156), relu
    gemm(mol_x, W1, bufA, N_MOL, 78, 156);
    k_node_alpha<2><<<N_MOL, 64, 0, stream>>>(bufA, as1, ad1, asb, adb, 78);
    k_gat_agg<3, 2><<<N_MOL, 64, 0, stream>>>(bufA, asb, adb, mol_rowp, mol_csrc, b1, bufB, 78, 1);
    // conv2: GAT 156 -> 156, H=2 (HC=312), relu
    gemm(bufB, W2, bufC, N_MOL, 156, 312);
    k_node_alpha<2><<<N_MOL, 64, 0, stream>>>(bufC, as2, ad2, asb, adb, 156);
    k_gat_agg<5, 2><<<N_MOL, 64, 0, stream>>>(bufC, asb, adb, mol_rowp, mol_csrc, b2, bufA, 156, 1);
    // conv3: GAT 312 -> 312, H=1, no relu
    gemm(bufA, W3, bufC, N_MOL, 312, 312);
    k_node_alpha<1><<<N_MOL, 64, 0, stream>>>(bufC, as3, ad3, asb, adb, 312);
    k_gat_agg<5, 1><<<N_MOL, 64, 0, stream>>>(bufC, asb, adb, mol_rowp, mol_csrc, b3, out_mol, 312, 0);

    // ---- pro branch ----
    // gcn: 33 -> 33, relu
    gemm(pro_x, Wp1, bufA, N_PRO, 33, 33);
    k_gcn_agg<<<N_PRO, 64, 0, stream>>>(bufA, dinv, pro_rowp, pro_csrc, pro_csrw, bp1, bufB, 33);
    // conv2: GAT 33 -> 66, H=2 (HC=132), relu
    gemm(bufB, Wp2, bufC, N_PRO, 33, 132);
    k_node_alpha<2><<<N_PRO, 64, 0, stream>>>(bufC, aps2, apd2, asb, adb, 66);
    k_gat_agg<3, 2><<<N_PRO, 64, 0, stream>>>(bufC, asb, adb, pro_rowp, pro_csrc, bp2, bufA, 66, 1);
    // conv3: GAT 132 -> 132, H=1, relu
    gemm(bufA, Wp3, bufC, N_PRO, 132, 132);
    k_node_alpha<1><<<N_PRO, 64, 0, stream>>>(bufC, aps3, apd3, asb, adb, 132);
    k_gat_agg<3, 1><<<N_PRO, 64, 0, stream>>>(bufC, asb, adb, pro_rowp, pro_csrc, bp3, out_pro, 132, 1);
}

// Round 2
// 1346.900 us; speedup vs baseline: 1.4473x; 1.4473x over previous
//
#include <hip/hip_runtime.h>
#include <cstdint>
#include <cstddef>

#define WAVE 64

typedef short s16x8 __attribute__((ext_vector_type(8)));
typedef float f32x4 __attribute__((ext_vector_type(4)));

__device__ __forceinline__ unsigned short f2bf(float f) {
    unsigned int u = __float_as_uint(f);
    unsigned int r = (u + 0x7fffu + ((u >> 16) & 1u)) >> 16;
    return (unsigned short)r;
}

// ---------------- CSR construction ----------------

__global__ __launch_bounds__(256) void k_count(const int* __restrict__ dst, int* __restrict__ cnt,
                                               const float* __restrict__ w, float* __restrict__ deg, int E) {
    int e = blockIdx.x * 256 + threadIdx.x;
    if (e < E) {
        int d = dst[e];
        atomicAdd(&cnt[d], 1);
        if (w) atomicAdd(&deg[d], w[e]);
    }
}

__global__ __launch_bounds__(256) void k_scan1(const int* __restrict__ cnt, int* __restrict__ incl,
                                               int* __restrict__ bsums, int n) {
    __shared__ int sm[256];
    int i = blockIdx.x * 256 + threadIdx.x;
    int v = (i < n) ? cnt[i] : 0;
    sm[threadIdx.x] = v;
    __syncthreads();
    for (int off = 1; off < 256; off <<= 1) {
        int t = (threadIdx.x >= off) ? sm[threadIdx.x - off] : 0;
        __syncthreads();
        sm[threadIdx.x] += t;
        __syncthreads();
    }
    if (i < n) incl[i] = sm[threadIdx.x];
    if (threadIdx.x == 255) bsums[blockIdx.x] = sm[255];
}

__global__ __launch_bounds__(512) void k_scan2(int* __restrict__ bsums, int nb) {
    __shared__ int sm[512];
    int v = (threadIdx.x < nb) ? bsums[threadIdx.x] : 0;
    sm[threadIdx.x] = v;
    __syncthreads();
    for (int off = 1; off < 512; off <<= 1) {
        int t = (threadIdx.x >= off) ? sm[threadIdx.x - off] : 0;
        __syncthreads();
        sm[threadIdx.x] += t;
        __syncthreads();
    }
    if (threadIdx.x < nb) bsums[threadIdx.x] = sm[threadIdx.x] - v;  // exclusive
}

__global__ __launch_bounds__(256) void k_scan3(const int* __restrict__ incl, const int* __restrict__ cnt,
                                               const int* __restrict__ boff, int* __restrict__ rowp,
                                               int* __restrict__ cur, int n, int Etot) {
    int i = blockIdx.x * 256 + threadIdx.x;
    if (i < n) {
        int ex = incl[i] - cnt[i] + boff[blockIdx.x];
        rowp[i] = ex;
        cur[i] = ex;
    }
    if (i == 0) rowp[n] = Etot;
}

__global__ __launch_bounds__(256) void k_scatter(const int* __restrict__ src, const int* __restrict__ dst,
                                                 const float* __restrict__ w, int* __restrict__ cur,
                                                 int* __restrict__ csrc, float* __restrict__ cw, int E) {
    int e = blockIdx.x * 256 + threadIdx.x;
    if (e < E) {
        int d = dst[e];
        int pos = atomicAdd(&cur[d], 1);
        csrc[pos] = src[e];
        if (w) cw[pos] = w[e];
    }
}

__global__ __launch_bounds__(256) void k_dinv(const float* __restrict__ deg, float* __restrict__ dinv, int N) {
    int i = blockIdx.x * 256 + threadIdx.x;
    if (i < N) dinv[i] = rsqrtf(deg[i] + 1.0f);
}

// ---------------- conversions ----------------

// fp32 [N,K] -> bf16 [N,Kp] (zero-padded)
__global__ __launch_bounds__(256) void k_cvt_x(const float* __restrict__ in, unsigned short* __restrict__ out,
                                               int K, int Kp, long long total) {
    long long idx = (long long)blockIdx.x * 256 + threadIdx.x;
    if (idx < total) {
        int n = (int)(idx / Kp);
        int k = (int)(idx - (long long)n * Kp);
        out[idx] = (k < K) ? f2bf(in[(long long)n * K + k]) : (unsigned short)0;
    }
}

// W fp32 [K,M] -> WT bf16 [M,Kp]
__global__ __launch_bounds__(256) void k_cvt_w(const float* __restrict__ W, unsigned short* __restrict__ WT,
                                               int K, int M, int Kp) {
    int idx = blockIdx.x * 256 + threadIdx.x;
    if (idx < M * Kp) {
        int m = idx / Kp;
        int k = idx - m * Kp;
        WT[idx] = (k < K) ? f2bf(W[(long long)k * M + m]) : (unsigned short)0;
    }
}

// ---------------- bf16 MFMA GEMM: C[N,M] = A[N,Kp] * BT[M,Kp]^T ----------------
// 128x128 block tile, BK=32, 256 threads (4 waves, 2x2), 4x4 16x16x32 MFMA per wave.

#define TBM 128
#define TBN 128
#define TBK 32
#define LDK 40  // padded LDS k-stride (80B, 16B aligned, bank-spread)

__global__ __launch_bounds__(256) void k_mfma_gemm(const unsigned short* __restrict__ A,
                                                   const unsigned short* __restrict__ BT,
                                                   float* __restrict__ C, int N, int Kp, int M) {
    __shared__ __align__(16) unsigned short As[TBM * LDK];
    __shared__ __align__(16) unsigned short Bs[TBN * LDK];
    int tid = threadIdx.x;
    int wave = tid >> 6;
    int lane = tid & 63;
    int rowBase = blockIdx.y * TBM;
    int colBase = blockIdx.x * TBN;
    int wm = (wave & 1) * 64;
    int wn = (wave >> 1) * 64;
    int l15 = lane & 15;
    int quad = lane >> 4;

    f32x4 acc[4][4];
    f32x4 z4 = {0.f, 0.f, 0.f, 0.f};
#pragma unroll
    for (int i = 0; i < 4; i++)
#pragma unroll
        for (int j = 0; j < 4; j++) acc[i][j] = z4;

    // staging: chunk = 8 bf16 (16B). 128 rows x 4 chunks = 512 chunks; 2 per thread.
    int srow = tid >> 2;       // 0..63
    int skg = tid & 3;         // 0..3
    const uint4 zero16 = {0u, 0u, 0u, 0u};

    for (int k0 = 0; k0 < Kp; k0 += TBK) {
#pragma unroll
        for (int half = 0; half < 2; half++) {
            int row = srow + half * 64;
            int gk = k0 + skg * 8;
            bool kok = (gk < Kp);
            // A tile
            {
                int gr = rowBase + row;
                uint4 v = zero16;
                if (kok && gr < N) v = *(const uint4*)(A + (size_t)gr * Kp + gk);
                *(uint4*)(As + row * LDK + skg * 8) = v;
            }
            // B tile (BT rows are output cols)
            {
                int gc = colBase + row;
                uint4 v = zero16;
                if (kok && gc < M) v = *(const uint4*)(BT + (size_t)gc * Kp + gk);
                *(uint4*)(Bs + row * LDK + skg * 8) = v;
            }
        }
        __syncthreads();

        s16x8 af[4], bfr[4];
#pragma unroll
        for (int mt = 0; mt < 4; mt++)
            af[mt] = *(const s16x8*)(As + (wm + mt * 16 + l15) * LDK + quad * 8);
#pragma unroll
        for (int nt = 0; nt < 4; nt++)
            bfr[nt] = *(const s16x8*)(Bs + (wn + nt * 16 + l15) * LDK + quad * 8);
#pragma unroll
        for (int mt = 0; mt < 4; mt++)
#pragma unroll
            for (int nt = 0; nt < 4; nt++)
                acc[mt][nt] = __builtin_amdgcn_mfma_f32_16x16x32_bf16(af[mt], bfr[nt], acc[mt][nt], 0, 0, 0);
        __syncthreads();
    }

#pragma unroll
    for (int mt = 0; mt < 4; mt++) {
#pragma unroll
        for (int r = 0; r < 4; r++) {
            int row = rowBase + wm + mt * 16 + quad * 4 + r;
            if (row < N) {
#pragma unroll
                for (int nt = 0; nt < 4; nt++) {
                    int col = colBase + wn + nt * 16 + l15;
                    if (col < M) C[(size_t)row * M + col] = acc[mt][nt][r];
                }
            }
        }
    }
}

// ---------------- per-node attention dots ----------------

template <int H>
__global__ __launch_bounds__(64) void k_node_alpha(const float* __restrict__ hfeat,
                                                   const float* __restrict__ a_src,
                                                   const float* __restrict__ a_dst,
                                                   float* __restrict__ as_out, float* __restrict__ ad_out,
                                                   int C) {
    int n = blockIdx.x;
    int lane = threadIdx.x;
    int HC = H * C;
    float ps[H], pd[H];
#pragma unroll
    for (int h = 0; h < H; h++) { ps[h] = 0.f; pd[h] = 0.f; }
    for (int c = lane; c < HC; c += 64) {
        float v = hfeat[(size_t)n * HC + c];
        int hd = c / C;
        ps[hd] += v * a_src[c];
        pd[hd] += v * a_dst[c];
    }
#pragma unroll
    for (int h = 0; h < H; h++) {
        float x = ps[h], y = pd[h];
        for (int off = 32; off > 0; off >>= 1) {
            x += __shfl_down(x, off);
            y += __shfl_down(y, off);
        }
        if (lane == 0) {
            as_out[(size_t)n * H + h] = x;
            ad_out[(size_t)n * H + h] = y;
        }
    }
}

// ---------------- GAT aggregation (one wave per dst node) ----------------

__device__ __forceinline__ float lrelu02(float e) { return (e > 0.f) ? e : 0.2f * e; }

template <int CPT, int H>
__global__ __launch_bounds__(64) void k_gat_agg(const float* __restrict__ hfeat,
                                                const float* __restrict__ as_, const float* __restrict__ ad_,
                                                const int* __restrict__ rowp, const int* __restrict__ cidx,
                                                const float* __restrict__ bias,
                                                float* __restrict__ out_f,            // final fp32 (or null)
                                                unsigned short* __restrict__ out_bf,  // next-layer bf16 (or null)
                                                int C, int Kpn, int relu) {
    int n = blockIdx.x;
    int lane = threadIdx.x;
    int HC = H * C;
    int beg = rowp[n], end = rowp[n + 1];

    int hd[CPT];
#pragma unroll
    for (int k = 0; k < CPT; k++) {
        int c = lane + k * WAVE;
        hd[k] = (c < HC) ? (c / C) : 0;
    }

    float adn[H], m[H];
#pragma unroll
    for (int h = 0; h < H; h++) {
        adn[h] = ad_[(size_t)n * H + h];
        m[h] = lrelu02(as_[(size_t)n * H + h] + adn[h]);  // self-loop logit
    }
    for (int j = beg; j < end; j++) {
        int s = cidx[j];
#pragma unroll
        for (int h = 0; h < H; h++) {
            float e = lrelu02(as_[(size_t)s * H + h] + adn[h]);
            m[h] = fmaxf(m[h], e);
        }
    }
    float acc[CPT];
#pragma unroll
    for (int k = 0; k < CPT; k++) acc[k] = 0.f;
    float ssum[H];
#pragma unroll
    for (int h = 0; h < H; h++) ssum[h] = 0.f;
    {
        float w[H];
#pragma unroll
        for (int h = 0; h < H; h++) {
            float e = lrelu02(as_[(size_t)n * H + h] + adn[h]);
            w[h] = expf(e - m[h]);
            ssum[h] += w[h];
        }
#pragma unroll
        for (int k = 0; k < CPT; k++) {
            int c = lane + k * WAVE;
            if (c < HC) acc[k] += w[hd[k]] * hfeat[(size_t)n * HC + c];
        }
    }
    for (int j = beg; j < end; j++) {
        int s = cidx[j];
        float w[H];
#pragma unroll
        for (int h = 0; h < H; h++) {
            float e = lrelu02(as_[(size_t)s * H + h] + adn[h]);
            w[h] = expf(e - m[h]);
            ssum[h] += w[h];
        }
#pragma unroll
        for (int k = 0; k < CPT; k++) {
            int c = lane + k * WAVE;
            if (c < HC) acc[k] += w[hd[k]] * hfeat[(size_t)s * HC + c];
        }
    }
#pragma unroll
    for (int k = 0; k < CPT; k++) {
        int c = lane + k * WAVE;
        if (c < HC) {
            float o = acc[k] / (ssum[hd[k]] + 1e-16f) + bias[c];
            if (relu) o = fmaxf(o, 0.f);
            if (out_bf) out_bf[(size_t)n * Kpn + c] = f2bf(o);
            else out_f[(size_t)n * HC + c] = o;
        } else if (out_bf && c < Kpn) {
            out_bf[(size_t)n * Kpn + c] = 0;
        }
    }
}

// ---------------- GCN aggregation (one wave per dst node, C<=64), bf16 out ----------------

__global__ __launch_bounds__(64) void k_gcn_agg(const float* __restrict__ hfeat, const float* __restrict__ dinv,
                                                const int* __restrict__ rowp, const int* __restrict__ cidx,
                                                const float* __restrict__ cw, const float* __restrict__ bias,
                                                unsigned short* __restrict__ out_bf, int C, int Kpn) {
    int n = blockIdx.x;
    int lane = threadIdx.x;
    float di = dinv[n];
    int beg = rowp[n], end = rowp[n + 1];
    float acc = 0.f;
    bool act = (lane < C);
    if (act) acc = di * di * hfeat[(size_t)n * C + lane];  // self loop, w=1
    for (int j = beg; j < end; j++) {
        int s = cidx[j];
        float nm = dinv[s] * cw[j] * di;
        if (act) acc += nm * hfeat[(size_t)s * C + lane];
    }
    if (act) out_bf[(size_t)n * Kpn + lane] = f2bf(fmaxf(acc + bias[lane], 0.f));
    else if (lane < Kpn) out_bf[(size_t)n * Kpn + lane] = 0;
}

// ---------------- launch ----------------

extern "C" void kernel_launch(void* const* d_in, const int* in_sizes, int n_in,
                              void* d_out, int out_size, void* d_ws, size_t ws_size,
                              hipStream_t stream) {
    const int N_MOL = in_sizes[0] / 78;
    const int E_MOL = in_sizes[1] / 2;
    const int N_PRO = in_sizes[2] / 33;
    const int E_PRO = in_sizes[3] / 2;

    const float* mol_x = (const float*)d_in[0];
    const int* mol_ei = (const int*)d_in[1];
    const float* pro_x = (const float*)d_in[2];
    const int* pro_ei = (const int*)d_in[3];
    const float* pro_ew = (const float*)d_in[4];
    const float *W1 = (const float*)d_in[5], *as1 = (const float*)d_in[6], *ad1 = (const float*)d_in[7],
                *b1 = (const float*)d_in[8];
    const float *W2 = (const float*)d_in[9], *as2 = (const float*)d_in[10], *ad2 = (const float*)d_in[11],
                *b2 = (const float*)d_in[12];
    const float *W3 = (const float*)d_in[13], *as3 = (const float*)d_in[14], *ad3 = (const float*)d_in[15],
                *b3 = (const float*)d_in[16];
    const float *Wp1 = (const float*)d_in[17], *bp1 = (const float*)d_in[18];
    const float *Wp2 = (const float*)d_in[19], *aps2 = (const float*)d_in[20], *apd2 = (const float*)d_in[21],
                *bp2 = (const float*)d_in[22];
    const float *Wp3 = (const float*)d_in[23], *aps3 = (const float*)d_in[24], *apd3 = (const float*)d_in[25],
                *bp3 = (const float*)d_in[26];

    float* out_mol = (float*)d_out;
    float* out_pro = (float*)d_out + (size_t)N_MOL * 312;

    char* p = (char*)d_ws;
    auto alloc = [&](size_t bytes) -> void* {
        void* r = (void*)p;
        p += (bytes + 255) & ~(size_t)255;
        return r;
    };
    int* mol_rowp = (int*)alloc((size_t)(N_MOL + 1) * 4);
    int* mol_cur  = (int*)alloc((size_t)N_MOL * 4);
    int* mol_cnt  = (int*)alloc((size_t)N_MOL * 4);
    int* mol_csrc = (int*)alloc((size_t)E_MOL * 4);
    int* pro_rowp = (int*)alloc((size_t)(N_PRO + 1) * 4);
    int* pro_cur  = (int*)alloc((size_t)N_PRO * 4);
    int* pro_cnt  = (int*)alloc((size_t)N_PRO * 4);
    int* pro_csrc = (int*)alloc((size_t)E_PRO * 4);
    float* pro_csrw = (float*)alloc((size_t)E_PRO * 4);
    float* deg  = (float*)alloc((size_t)N_PRO * 4);
    float* dinv = (float*)alloc((size_t)N_PRO * 4);
    int* incl  = (int*)alloc((size_t)N_PRO * 4);
    int* bsums = (int*)alloc(512 * 4);
    float* asb = (float*)alloc((size_t)N_PRO * 2 * 4);
    float* adb = (float*)alloc((size_t)N_PRO * 2 * 4);
    float* hbuf = (float*)alloc((size_t)N_MOL * 312 * 4);        // GEMM output (62.4MB, reused)
    unsigned short* xb = (unsigned short*)alloc((size_t)N_MOL * 320 * 2);  // bf16 activations (32MB, reused)
    unsigned short* wt1 = (unsigned short*)alloc((size_t)156 * 80 * 2);
    unsigned short* wt2 = (unsigned short*)alloc((size_t)312 * 160 * 2);
    unsigned short* wt3 = (unsigned short*)alloc((size_t)312 * 320 * 2);
    unsigned short* wtp1 = (unsigned short*)alloc((size_t)33 * 40 * 2);
    unsigned short* wtp2 = (unsigned short*)alloc((size_t)132 * 40 * 2);
    unsigned short* wtp3 = (unsigned short*)alloc((size_t)132 * 136 * 2);
    (void)ws_size;

    const int* mol_src = mol_ei;
    const int* mol_dst = mol_ei + E_MOL;
    const int* pro_src = pro_ei;
    const int* pro_dst = pro_ei + E_PRO;

    // ---- build CSR (by dst) ----
    hipMemsetAsync(mol_cnt, 0, (size_t)N_MOL * 4, stream);
    hipMemsetAsync(pro_cnt, 0, (size_t)N_PRO * 4, stream);
    hipMemsetAsync(deg, 0, (size_t)N_PRO * 4, stream);

    k_count<<<(E_MOL + 255) / 256, 256, 0, stream>>>(mol_dst, mol_cnt, nullptr, nullptr, E_MOL);
    k_count<<<(E_PRO + 255) / 256, 256, 0, stream>>>(pro_dst, pro_cnt, pro_ew, deg, E_PRO);

    int nbM = (N_MOL + 255) / 256;
    k_scan1<<<nbM, 256, 0, stream>>>(mol_cnt, incl, bsums, N_MOL);
    k_scan2<<<1, 512, 0, stream>>>(bsums, nbM);
    k_scan3<<<nbM, 256, 0, stream>>>(incl, mol_cnt, bsums, mol_rowp, mol_cur, N_MOL, E_MOL);
    k_scatter<<<(E_MOL + 255) / 256, 256, 0, stream>>>(mol_src, mol_dst, nullptr, mol_cur, mol_csrc, nullptr, E_MOL);

    int nbP = (N_PRO + 255) / 256;
    k_scan1<<<nbP, 256, 0, stream>>>(pro_cnt, incl, bsums, N_PRO);
    k_scan2<<<1, 512, 0, stream>>>(bsums, nbP);
    k_scan3<<<nbP, 256, 0, stream>>>(incl, pro_cnt, bsums, pro_rowp, pro_cur, N_PRO, E_PRO);
    k_scatter<<<(E_PRO + 255) / 256, 256, 0, stream>>>(pro_src, pro_dst, pro_ew, pro_cur, pro_csrc, pro_csrw, E_PRO);

    k_dinv<<<(N_PRO + 255) / 256, 256, 0, stream>>>(deg, dinv, N_PRO);

    // ---- weight converts (W[K,M] -> WT bf16 [M,Kp]) ----
    auto cvtw = [&](const float* W, unsigned short* WT, int K, int M, int Kp) {
        k_cvt_w<<<(M * Kp + 255) / 256, 256, 0, stream>>>(W, WT, K, M, Kp);
    };
    cvtw(W1, wt1, 78, 156, 80);
    cvtw(W2, wt2, 156, 312, 160);
    cvtw(W3, wt3, 312, 312, 320);
    cvtw(Wp1, wtp1, 33, 33, 40);
    cvtw(Wp2, wtp2, 33, 132, 40);
    cvtw(Wp3, wtp3, 132, 132, 136);

    auto gemm = [&](const unsigned short* A, const unsigned short* BT, float* C, int N, int Kp, int M) {
        dim3 grid((M + TBN - 1) / TBN, (N + TBM - 1) / TBM);
        k_mfma_gemm<<<grid, 256, 0, stream>>>(A, BT, C, N, Kp, M);
    };

    // ---- mol branch ----
    {
        long long tot = (long long)N_MOL * 80;
        k_cvt_x<<<(int)((tot + 255) / 256), 256, 0, stream>>>(mol_x, xb, 78, 80, tot);
    }
    // conv1: GAT 78 -> 78, H=2 (HC=156), relu -> bf16 [N,160]
    gemm(xb, wt1, hbuf, N_MOL, 80, 156);
    k_node_alpha<2><<<N_MOL, 64, 0, stream>>>(hbuf, as1, ad1, asb, adb, 78);
    k_gat_agg<3, 2><<<N_MOL, 64, 0, stream>>>(hbuf, asb, adb, mol_rowp, mol_csrc, b1, nullptr, xb, 78, 160, 1);
    // conv2: GAT 156 -> 156, H=2 (HC=312), relu -> bf16 [N,320]
    gemm(xb, wt2, hbuf, N_MOL, 160, 312);
    k_node_alpha<2><<<N_MOL, 64, 0, stream>>>(hbuf, as2, ad2, asb, adb, 156);
    k_gat_agg<5, 2><<<N_MOL, 64, 0, stream>>>(hbuf, asb, adb, mol_rowp, mol_csrc, b2, nullptr, xb, 156, 320, 1);
    // conv3: GAT 312 -> 312, H=1, no relu -> fp32 out
    gemm(xb, wt3, hbuf, N_MOL, 320, 312);
    k_node_alpha<1><<<N_MOL, 64, 0, stream>>>(hbuf, as3, ad3, asb, adb, 312);
    k_gat_agg<5, 1><<<N_MOL, 64, 0, stream>>>(hbuf, asb, adb, mol_rowp, mol_csrc, b3, out_mol, nullptr, 312, 0, 0);

    // ---- pro branch ----
    {
        long long tot = (long long)N_PRO * 40;
        k_cvt_x<<<(int)((tot + 255) / 256), 256, 0, stream>>>(pro_x, xb, 33, 40, tot);
    }
    // gcn: 33 -> 33, relu -> bf16 [N,40]
    gemm(xb, wtp1, hbuf, N_PRO, 40, 33);
    k_gcn_agg<<<N_PRO, 64, 0, stream>>>(hbuf, dinv, pro_rowp, pro_csrc, pro_csrw, bp1, xb, 33, 40);
    // conv2: GAT 33 -> 66, H=2 (HC=132), relu -> bf16 [N,136]
    gemm(xb, wtp2, hbuf, N_PRO, 40, 132);
    k_node_alpha<2><<<N_PRO, 64, 0, stream>>>(hbuf, aps2, apd2, asb, adb, 66);
    k_gat_agg<3, 2><<<N_PRO, 64, 0, stream>>>(hbuf, asb, adb, pro_rowp, pro_csrc, bp2, nullptr, xb, 66, 136, 1);
    // conv3: GAT 132 -> 132, H=1, relu -> fp32 out
    gemm(xb, wtp3, hbuf, N_PRO, 136, 132);
    k_node_alpha<1><<<N_PRO, 64, 0, stream>>>(hbuf, aps3, apd3, asb, adb, 132);
    k_gat_agg<3, 1><<<N_PRO, 64, 0, stream>>>(hbuf, asb, adb, pro_rowp, pro_csrc, bp3, out_pro, nullptr, 132, 0, 1);
}

// Round 3
// 1071.666 us; speedup vs baseline: 1.8190x; 1.2568x over previous
//
#include <hip/hip_runtime.h>
#include <cstdint>
#include <cstddef>

#define WAVE 64

typedef short s16x8 __attribute__((ext_vector_type(8)));
typedef float f32x4 __attribute__((ext_vector_type(4)));

__device__ __forceinline__ unsigned short f2bf(float f) {
    unsigned int u = __float_as_uint(f);
    unsigned int r = (u + 0x7fffu + ((u >> 16) & 1u)) >> 16;
    return (unsigned short)r;
}
__device__ __forceinline__ float bf2f_lo(unsigned int v) { return __uint_as_float(v << 16); }
__device__ __forceinline__ float bf2f_hi(unsigned int v) { return __uint_as_float(v & 0xffff0000u); }

// ---------------- CSR construction ----------------

__global__ __launch_bounds__(256) void k_count(const int* __restrict__ dst, int* __restrict__ cnt,
                                               const float* __restrict__ w, float* __restrict__ deg, int E) {
    int e = blockIdx.x * 256 + threadIdx.x;
    if (e < E) {
        int d = dst[e];
        atomicAdd(&cnt[d], 1);
        if (w) atomicAdd(&deg[d], w[e]);
    }
}

__global__ __launch_bounds__(256) void k_scan1(const int* __restrict__ cnt, int* __restrict__ incl,
                                               int* __restrict__ bsums, int n) {
    __shared__ int sm[256];
    int i = blockIdx.x * 256 + threadIdx.x;
    int v = (i < n) ? cnt[i] : 0;
    sm[threadIdx.x] = v;
    __syncthreads();
    for (int off = 1; off < 256; off <<= 1) {
        int t = (threadIdx.x >= off) ? sm[threadIdx.x - off] : 0;
        __syncthreads();
        sm[threadIdx.x] += t;
        __syncthreads();
    }
    if (i < n) incl[i] = sm[threadIdx.x];
    if (threadIdx.x == 255) bsums[blockIdx.x] = sm[255];
}

__global__ __launch_bounds__(512) void k_scan2(int* __restrict__ bsums, int nb) {
    __shared__ int sm[512];
    int v = (threadIdx.x < nb) ? bsums[threadIdx.x] : 0;
    sm[threadIdx.x] = v;
    __syncthreads();
    for (int off = 1; off < 512; off <<= 1) {
        int t = (threadIdx.x >= off) ? sm[threadIdx.x - off] : 0;
        __syncthreads();
        sm[threadIdx.x] += t;
        __syncthreads();
    }
    if (threadIdx.x < nb) bsums[threadIdx.x] = sm[threadIdx.x] - v;  // exclusive
}

__global__ __launch_bounds__(256) void k_scan3(const int* __restrict__ incl, const int* __restrict__ cnt,
                                               const int* __restrict__ boff, int* __restrict__ rowp,
                                               int* __restrict__ cur, int n, int Etot) {
    int i = blockIdx.x * 256 + threadIdx.x;
    if (i < n) {
        int ex = incl[i] - cnt[i] + boff[blockIdx.x];
        rowp[i] = ex;
        cur[i] = ex;
    }
    if (i == 0) rowp[n] = Etot;
}

__global__ __launch_bounds__(256) void k_scatter(const int* __restrict__ src, const int* __restrict__ dst,
                                                 const float* __restrict__ w, int* __restrict__ cur,
                                                 int* __restrict__ csrc, float* __restrict__ cw, int E) {
    int e = blockIdx.x * 256 + threadIdx.x;
    if (e < E) {
        int d = dst[e];
        int pos = atomicAdd(&cur[d], 1);
        csrc[pos] = src[e];
        if (w) cw[pos] = w[e];
    }
}

__global__ __launch_bounds__(256) void k_dinv(const float* __restrict__ deg, float* __restrict__ dinv, int N) {
    int i = blockIdx.x * 256 + threadIdx.x;
    if (i < N) dinv[i] = rsqrtf(deg[i] + 1.0f);
}

// ---------------- conversions ----------------

__global__ __launch_bounds__(256) void k_cvt_x(const float* __restrict__ in, unsigned short* __restrict__ out,
                                               int K, int Kp, long long total) {
    long long idx = (long long)blockIdx.x * 256 + threadIdx.x;
    if (idx < total) {
        int n = (int)(idx / Kp);
        int k = (int)(idx - (long long)n * Kp);
        out[idx] = (k < K) ? f2bf(in[(long long)n * K + k]) : (unsigned short)0;
    }
}

// W fp32 [K,M] -> WT bf16 [M,Kp]
__global__ __launch_bounds__(256) void k_cvt_w(const float* __restrict__ W, unsigned short* __restrict__ WT,
                                               int K, int M, int Kp) {
    int idx = blockIdx.x * 256 + threadIdx.x;
    if (idx < M * Kp) {
        int m = idx / Kp;
        int k = idx - m * Kp;
        WT[idx] = (k < K) ? f2bf(W[(long long)k * M + m]) : (unsigned short)0;
    }
}

// ---------------- bf16 MFMA GEMM: Cbf[N,Mp] = A[N,Kp] * BT[M,Kp]^T (bf16 out) ----------------

#define TBM 128
#define TBN 128
#define TBK 32
#define LDK 40

__global__ __launch_bounds__(256) void k_mfma_gemm(const unsigned short* __restrict__ A,
                                                   const unsigned short* __restrict__ BT,
                                                   unsigned short* __restrict__ Cbf,
                                                   int N, int Kp, int M, int Mp) {
    __shared__ __align__(16) unsigned short As[TBM * LDK];
    __shared__ __align__(16) unsigned short Bs[TBN * LDK];
    int tid = threadIdx.x;
    int wave = tid >> 6;
    int lane = tid & 63;
    int rowBase = blockIdx.y * TBM;
    int colBase = blockIdx.x * TBN;
    int wm = (wave & 1) * 64;
    int wn = (wave >> 1) * 64;
    int l15 = lane & 15;
    int quad = lane >> 4;

    f32x4 acc[4][4];
    f32x4 z4 = {0.f, 0.f, 0.f, 0.f};
#pragma unroll
    for (int i = 0; i < 4; i++)
#pragma unroll
        for (int j = 0; j < 4; j++) acc[i][j] = z4;

    int srow = tid >> 2;
    int skg = tid & 3;
    const uint4 zero16 = {0u, 0u, 0u, 0u};

    for (int k0 = 0; k0 < Kp; k0 += TBK) {
#pragma unroll
        for (int half = 0; half < 2; half++) {
            int row = srow + half * 64;
            int gk = k0 + skg * 8;
            bool kok = (gk < Kp);
            {
                int gr = rowBase + row;
                uint4 v = zero16;
                if (kok && gr < N) v = *(const uint4*)(A + (size_t)gr * Kp + gk);
                *(uint4*)(As + row * LDK + skg * 8) = v;
            }
            {
                int gc = colBase + row;
                uint4 v = zero16;
                if (kok && gc < M) v = *(const uint4*)(BT + (size_t)gc * Kp + gk);
                *(uint4*)(Bs + row * LDK + skg * 8) = v;
            }
        }
        __syncthreads();

        s16x8 af[4], bfr[4];
#pragma unroll
        for (int mt = 0; mt < 4; mt++)
            af[mt] = *(const s16x8*)(As + (wm + mt * 16 + l15) * LDK + quad * 8);
#pragma unroll
        for (int nt = 0; nt < 4; nt++)
            bfr[nt] = *(const s16x8*)(Bs + (wn + nt * 16 + l15) * LDK + quad * 8);
#pragma unroll
        for (int mt = 0; mt < 4; mt++)
#pragma unroll
            for (int nt = 0; nt < 4; nt++)
                acc[mt][nt] = __builtin_amdgcn_mfma_f32_16x16x32_bf16(af[mt], bfr[nt], acc[mt][nt], 0, 0, 0);
        __syncthreads();
    }

#pragma unroll
    for (int mt = 0; mt < 4; mt++) {
#pragma unroll
        for (int r = 0; r < 4; r++) {
            int row = rowBase + wm + mt * 16 + quad * 4 + r;
            if (row < N) {
#pragma unroll
                for (int nt = 0; nt < 4; nt++) {
                    int col = colBase + wn + nt * 16 + l15;
                    if (col < Mp) {
                        unsigned short o = (col < M) ? f2bf(acc[mt][nt][r]) : (unsigned short)0;
                        Cbf[(size_t)row * Mp + col] = o;
                    }
                }
            }
        }
    }
}

// ---------------- per-node attention dots (bf16 features) ----------------

template <int H>
__global__ __launch_bounds__(64) void k_node_alpha(const unsigned short* __restrict__ hfeat, int ldh,
                                                   const float* __restrict__ a_src,
                                                   const float* __restrict__ a_dst,
                                                   float* __restrict__ as_out, float* __restrict__ ad_out,
                                                   int C) {
    int n = blockIdx.x;
    int lane = threadIdx.x;
    int HC = H * C;
    float ps[H], pd[H];
#pragma unroll
    for (int h = 0; h < H; h++) { ps[h] = 0.f; pd[h] = 0.f; }
    for (int c2 = 2 * lane; c2 < HC; c2 += 128) {
        unsigned int v = *(const unsigned int*)(hfeat + (size_t)n * ldh + c2);
        float f0 = bf2f_lo(v), f1 = bf2f_hi(v);
        int hd = c2 / C;  // C even -> pair same head
        ps[hd] += f0 * a_src[c2] + f1 * a_src[c2 + 1];
        pd[hd] += f0 * a_dst[c2] + f1 * a_dst[c2 + 1];
    }
#pragma unroll
    for (int h = 0; h < H; h++) {
        float x = ps[h], y = pd[h];
        for (int off = 32; off > 0; off >>= 1) {
            x += __shfl_down(x, off);
            y += __shfl_down(y, off);
        }
        if (lane == 0) {
            as_out[(size_t)n * H + h] = x;
            ad_out[(size_t)n * H + h] = y;
        }
    }
}

// ---------------- GAT aggregation: single pass, self-logit shift, bf16 gathers ----------------

__device__ __forceinline__ float lrelu02(float e) { return (e > 0.f) ? e : 0.2f * e; }

template <int CPT2, int H>
__global__ __launch_bounds__(64) void k_gat_agg(const unsigned short* __restrict__ hfeat,
                                                const float* __restrict__ as_, const float* __restrict__ ad_,
                                                const int* __restrict__ rowp, const int* __restrict__ cidx,
                                                const float* __restrict__ bias,
                                                float* __restrict__ out_f,            // final fp32 (or null)
                                                unsigned short* __restrict__ out_bf,  // next-layer bf16 (or null)
                                                int C, int ldh, int ldo, int relu) {
    int n = blockIdx.x;
    int lane = threadIdx.x;
    int HC = H * C;
    int beg = rowp[n], end = rowp[n + 1];

    int c2i[CPT2];
    bool act[CPT2];
    int hd[CPT2];
#pragma unroll
    for (int k = 0; k < CPT2; k++) {
        int c2 = 2 * (lane + k * WAVE);
        c2i[k] = c2;
        act[k] = (c2 < HC);
        hd[k] = act[k] ? (c2 / C) : 0;  // C even -> pair same head
    }

    float adn[H], msub[H], ssum[H];
#pragma unroll
    for (int h = 0; h < H; h++) {
        adn[h] = ad_[(size_t)n * H + h];
        msub[h] = lrelu02(as_[(size_t)n * H + h] + adn[h]);  // shift by self logit
        ssum[h] = 1.f;                                       // exp(0) self term
    }

    float accx[CPT2], accy[CPT2];
#pragma unroll
    for (int k = 0; k < CPT2; k++) {
        if (act[k]) {
            unsigned int v = *(const unsigned int*)(hfeat + (size_t)n * ldh + c2i[k]);
            accx[k] = bf2f_lo(v);
            accy[k] = bf2f_hi(v);
        } else {
            accx[k] = 0.f;
            accy[k] = 0.f;
        }
    }

    // software-pipelined edge loop: prefetch next index + next alpha
    int j = beg;
    int sN = (j < end) ? cidx[j] : 0;
    float aN[H];
#pragma unroll
    for (int h = 0; h < H; h++) aN[h] = (j < end) ? as_[(size_t)sN * H + h] : 0.f;

    for (; j < end; j++) {
        int s = sN;
        float a0[H];
#pragma unroll
        for (int h = 0; h < H; h++) a0[h] = aN[h];
        if (j + 1 < end) {
            sN = cidx[j + 1];
#pragma unroll
            for (int h = 0; h < H; h++) aN[h] = as_[(size_t)sN * H + h];
        }
        float w[H];
#pragma unroll
        for (int h = 0; h < H; h++) {
            w[h] = __expf(lrelu02(a0[h] + adn[h]) - msub[h]);
            ssum[h] += w[h];
        }
#pragma unroll
        for (int k = 0; k < CPT2; k++) {
            if (act[k]) {
                unsigned int v = *(const unsigned int*)(hfeat + (size_t)s * ldh + c2i[k]);
                accx[k] += w[hd[k]] * bf2f_lo(v);
                accy[k] += w[hd[k]] * bf2f_hi(v);
            }
        }
    }

    float rs[H];
#pragma unroll
    for (int h = 0; h < H; h++) rs[h] = 1.f / (ssum[h] + 1e-16f);

#pragma unroll
    for (int k = 0; k < CPT2; k++) {
        int c2 = c2i[k];
        if (act[k]) {
            float o0 = accx[k] * rs[hd[k]] + bias[c2];
            float o1 = accy[k] * rs[hd[k]] + bias[c2 + 1];
            if (relu) { o0 = fmaxf(o0, 0.f); o1 = fmaxf(o1, 0.f); }
            if (out_bf) {
                unsigned int pk = (unsigned int)f2bf(o0) | ((unsigned int)f2bf(o1) << 16);
                *(unsigned int*)(out_bf + (size_t)n * ldo + c2) = pk;
            } else {
                *(float2*)(out_f + (size_t)n * HC + c2) = make_float2(o0, o1);
            }
        } else if (out_bf && c2 < ldo) {
            *(unsigned int*)(out_bf + (size_t)n * ldo + c2) = 0u;
        }
    }
}

// ---------------- GCN aggregation (bf16 in/out, C<=64) ----------------

__global__ __launch_bounds__(64) void k_gcn_agg(const unsigned short* __restrict__ hfeat, int ldh,
                                                const float* __restrict__ dinv,
                                                const int* __restrict__ rowp, const int* __restrict__ cidx,
                                                const float* __restrict__ cw, const float* __restrict__ bias,
                                                unsigned short* __restrict__ out_bf, int C, int ldo) {
    int n = blockIdx.x;
    int lane = threadIdx.x;
    float di = dinv[n];
    int beg = rowp[n], end = rowp[n + 1];
    float acc = 0.f;
    bool actl = (lane < C);
    if (actl) acc = di * di * __uint_as_float((unsigned int)hfeat[(size_t)n * ldh + lane] << 16);
    for (int j = beg; j < end; j++) {
        int s = cidx[j];
        float nm = dinv[s] * cw[j] * di;
        if (actl) acc += nm * __uint_as_float((unsigned int)hfeat[(size_t)s * ldh + lane] << 16);
    }
    if (actl) out_bf[(size_t)n * ldo + lane] = f2bf(fmaxf(acc + bias[lane], 0.f));
    else if (lane < ldo) out_bf[(size_t)n * ldo + lane] = 0;
}

// ---------------- launch ----------------

extern "C" void kernel_launch(void* const* d_in, const int* in_sizes, int n_in,
                              void* d_out, int out_size, void* d_ws, size_t ws_size,
                              hipStream_t stream) {
    const int N_MOL = in_sizes[0] / 78;
    const int E_MOL = in_sizes[1] / 2;
    const int N_PRO = in_sizes[2] / 33;
    const int E_PRO = in_sizes[3] / 2;

    const float* mol_x = (const float*)d_in[0];
    const int* mol_ei = (const int*)d_in[1];
    const float* pro_x = (const float*)d_in[2];
    const int* pro_ei = (const int*)d_in[3];
    const float* pro_ew = (const float*)d_in[4];
    const float *W1 = (const float*)d_in[5], *as1 = (const float*)d_in[6], *ad1 = (const float*)d_in[7],
                *b1 = (const float*)d_in[8];
    const float *W2 = (const float*)d_in[9], *as2 = (const float*)d_in[10], *ad2 = (const float*)d_in[11],
                *b2 = (const float*)d_in[12];
    const float *W3 = (const float*)d_in[13], *as3 = (const float*)d_in[14], *ad3 = (const float*)d_in[15],
                *b3 = (const float*)d_in[16];
    const float *Wp1 = (const float*)d_in[17], *bp1 = (const float*)d_in[18];
    const float *Wp2 = (const float*)d_in[19], *aps2 = (const float*)d_in[20], *apd2 = (const float*)d_in[21],
                *bp2 = (const float*)d_in[22];
    const float *Wp3 = (const float*)d_in[23], *aps3 = (const float*)d_in[24], *apd3 = (const float*)d_in[25],
                *bp3 = (const float*)d_in[26];

    float* out_mol = (float*)d_out;
    float* out_pro = (float*)d_out + (size_t)N_MOL * 312;

    char* p = (char*)d_ws;
    auto alloc = [&](size_t bytes) -> void* {
        void* r = (void*)p;
        p += (bytes + 255) & ~(size_t)255;
        return r;
    };
    int* mol_rowp = (int*)alloc((size_t)(N_MOL + 1) * 4);
    int* mol_cur  = (int*)alloc((size_t)N_MOL * 4);
    int* mol_cnt  = (int*)alloc((size_t)N_MOL * 4);
    int* mol_csrc = (int*)alloc((size_t)E_MOL * 4);
    int* pro_rowp = (int*)alloc((size_t)(N_PRO + 1) * 4);
    int* pro_cur  = (int*)alloc((size_t)N_PRO * 4);
    int* pro_cnt  = (int*)alloc((size_t)N_PRO * 4);
    int* pro_csrc = (int*)alloc((size_t)E_PRO * 4);
    float* pro_csrw = (float*)alloc((size_t)E_PRO * 4);
    float* deg  = (float*)alloc((size_t)N_PRO * 4);
    float* dinv = (float*)alloc((size_t)N_PRO * 4);
    int* incl  = (int*)alloc((size_t)N_PRO * 4);
    int* bsums = (int*)alloc(512 * 4);
    float* asb = (float*)alloc((size_t)N_PRO * 2 * 4);
    float* adb = (float*)alloc((size_t)N_PRO * 2 * 4);
    unsigned short* hb = (unsigned short*)alloc((size_t)N_MOL * 320 * 2);  // GEMM out bf16
    unsigned short* xb = (unsigned short*)alloc((size_t)N_MOL * 320 * 2);  // activations bf16
    unsigned short* wt1 = (unsigned short*)alloc((size_t)156 * 80 * 2);
    unsigned short* wt2 = (unsigned short*)alloc((size_t)312 * 160 * 2);
    unsigned short* wt3 = (unsigned short*)alloc((size_t)312 * 320 * 2);
    unsigned short* wtp1 = (unsigned short*)alloc((size_t)33 * 40 * 2);
    unsigned short* wtp2 = (unsigned short*)alloc((size_t)132 * 40 * 2);
    unsigned short* wtp3 = (unsigned short*)alloc((size_t)132 * 136 * 2);
    (void)ws_size;

    const int* mol_src = mol_ei;
    const int* mol_dst = mol_ei + E_MOL;
    const int* pro_src = pro_ei;
    const int* pro_dst = pro_ei + E_PRO;

    // ---- build CSR (by dst) ----
    hipMemsetAsync(mol_cnt, 0, (size_t)N_MOL * 4, stream);
    hipMemsetAsync(pro_cnt, 0, (size_t)N_PRO * 4, stream);
    hipMemsetAsync(deg, 0, (size_t)N_PRO * 4, stream);

    k_count<<<(E_MOL + 255) / 256, 256, 0, stream>>>(mol_dst, mol_cnt, nullptr, nullptr, E_MOL);
    k_count<<<(E_PRO + 255) / 256, 256, 0, stream>>>(pro_dst, pro_cnt, pro_ew, deg, E_PRO);

    int nbM = (N_MOL + 255) / 256;
    k_scan1<<<nbM, 256, 0, stream>>>(mol_cnt, incl, bsums, N_MOL);
    k_scan2<<<1, 512, 0, stream>>>(bsums, nbM);
    k_scan3<<<nbM, 256, 0, stream>>>(incl, mol_cnt, bsums, mol_rowp, mol_cur, N_MOL, E_MOL);
    k_scatter<<<(E_MOL + 255) / 256, 256, 0, stream>>>(mol_src, mol_dst, nullptr, mol_cur, mol_csrc, nullptr, E_MOL);

    int nbP = (N_PRO + 255) / 256;
    k_scan1<<<nbP, 256, 0, stream>>>(pro_cnt, incl, bsums, N_PRO);
    k_scan2<<<1, 512, 0, stream>>>(bsums, nbP);
    k_scan3<<<nbP, 256, 0, stream>>>(incl, pro_cnt, bsums, pro_rowp, pro_cur, N_PRO, E_PRO);
    k_scatter<<<(E_PRO + 255) / 256, 256, 0, stream>>>(pro_src, pro_dst, pro_ew, pro_cur, pro_csrc, pro_csrw, E_PRO);

    k_dinv<<<(N_PRO + 255) / 256, 256, 0, stream>>>(deg, dinv, N_PRO);

    // ---- weight converts ----
    auto cvtw = [&](const float* W, unsigned short* WT, int K, int M, int Kp) {
        k_cvt_w<<<(M * Kp + 255) / 256, 256, 0, stream>>>(W, WT, K, M, Kp);
    };
    cvtw(W1, wt1, 78, 156, 80);
    cvtw(W2, wt2, 156, 312, 160);
    cvtw(W3, wt3, 312, 312, 320);
    cvtw(Wp1, wtp1, 33, 33, 40);
    cvtw(Wp2, wtp2, 33, 132, 40);
    cvtw(Wp3, wtp3, 132, 132, 136);

    auto gemm = [&](const unsigned short* A, const unsigned short* BT, unsigned short* C,
                    int N, int Kp, int M, int Mp) {
        dim3 grid((M + TBN - 1) / TBN, (N + TBM - 1) / TBM);
        k_mfma_gemm<<<grid, 256, 0, stream>>>(A, BT, C, N, Kp, M, Mp);
    };

    // ---- mol branch ----
    {
        long long tot = (long long)N_MOL * 80;
        k_cvt_x<<<(int)((tot + 255) / 256), 256, 0, stream>>>(mol_x, xb, 78, 80, tot);
    }
    // conv1: GAT 78 -> 78, H=2 (HC=156), relu
    gemm(xb, wt1, hb, N_MOL, 80, 156, 160);
    k_node_alpha<2><<<N_MOL, 64, 0, stream>>>(hb, 160, as1, ad1, asb, adb, 78);
    k_gat_agg<2, 2><<<N_MOL, 64, 0, stream>>>(hb, asb, adb, mol_rowp, mol_csrc, b1, nullptr, xb, 78, 160, 160, 1);
    // conv2: GAT 156 -> 156, H=2 (HC=312), relu
    gemm(xb, wt2, hb, N_MOL, 160, 312, 320);
    k_node_alpha<2><<<N_MOL, 64, 0, stream>>>(hb, 320, as2, ad2, asb, adb, 156);
    k_gat_agg<3, 2><<<N_MOL, 64, 0, stream>>>(hb, asb, adb, mol_rowp, mol_csrc, b2, nullptr, xb, 156, 320, 320, 1);
    // conv3: GAT 312 -> 312, H=1, no relu -> fp32 out
    gemm(xb, wt3, hb, N_MOL, 320, 312, 320);
    k_node_alpha<1><<<N_MOL, 64, 0, stream>>>(hb, 320, as3, ad3, asb, adb, 312);
    k_gat_agg<3, 1><<<N_MOL, 64, 0, stream>>>(hb, asb, adb, mol_rowp, mol_csrc, b3, out_mol, nullptr, 312, 320, 0, 0);

    // ---- pro branch ----
    {
        long long tot = (long long)N_PRO * 40;
        k_cvt_x<<<(int)((tot + 255) / 256), 256, 0, stream>>>(pro_x, xb, 33, 40, tot);
    }
    // gcn: 33 -> 33, relu
    gemm(xb, wtp1, hb, N_PRO, 40, 33, 40);
    k_gcn_agg<<<N_PRO, 64, 0, stream>>>(hb, 40, dinv, pro_rowp, pro_csrc, pro_csrw, bp1, xb, 33, 40);
    // conv2: GAT 33 -> 66, H=2 (HC=132), relu
    gemm(xb, wtp2, hb, N_PRO, 40, 132, 136);
    k_node_alpha<2><<<N_PRO, 64, 0, stream>>>(hb, 136, aps2, apd2, asb, adb, 66);
    k_gat_agg<2, 2><<<N_PRO, 64, 0, stream>>>(hb, asb, adb, pro_rowp, pro_csrc, bp2, nullptr, xb, 66, 136, 136, 1);
    // conv3: GAT 132 -> 132, H=1, relu -> fp32 out
    gemm(xb, wtp3, hb, N_PRO, 136, 132, 136);
    k_node_alpha<1><<<N_PRO, 64, 0, stream>>>(hb, 136, aps3, apd3, asb, adb, 132);
    k_gat_agg<2, 1><<<N_PRO, 64, 0, stream>>>(hb, asb, adb, pro_rowp, pro_csrc, bp3, out_pro, nullptr, 132, 136, 0, 1);
}